// Round 1
// baseline (347.788 us; speedup 1.0000x reference)
//
#include <hip/hip_runtime.h>

// Zero-phase bandpass FIR, collapsed to one 8191-tap correlation with the
// kernel autocorrelation g, run on MFMA as an implicit-Toeplitz GEMM.
//   out[t] = sum_{s=0}^{8190} g[s] * xe[t + s]
//   g[s]   = sum_i k[i] * k[i + 4095 - s]          (autocorrelation, symmetric)
//   xe[w]  = reflect-padded / zero-extended x at v = w - 4095
// Precision: g split into bf16 hi+lo (2 MFMA terms), x as bf16, fp32 accum.

#define T_LEN  131072
#define XE_LEN 139776        // T + 8704 (covers t0max + 32*264 + 271)
#define NCHUNK 273           // Toeplitz A chunks: p in [-8, 264], idx P = p + 8
#define QSTEPS 265

typedef float  f32x4  __attribute__((ext_vector_type(4)));
typedef __bf16 bf16x8 __attribute__((ext_vector_type(8)));

// ---------- ws layout (bytes) ----------
#define WS_KZ   0                       // 12288 floats  (zero-padded k)
#define WS_G    49152                   // 8192 floats   (autocorrelation)
#define WS_AHI  81920                   // 273*512 bf16  (Toeplitz frags, hi)
#define WS_ALO  361472                  // 273*512 bf16  (lo)
#define WS_XE   641024                  // 32*139776 bf16 (padded signal)
#define WS_END  9586688

// K0: kz[m] = k[m-4096] if in range else 0, m in [0,12288)
__global__ void k_build_kz(const float* __restrict__ k, float* __restrict__ kz) {
  int m = blockIdx.x * 256 + threadIdx.x;
  if (m < 12288) {
    int i = m - 4096;
    kz[m] = (i >= 0 && i < 4096) ? k[i] : 0.0f;
  }
}

// K1: g[s] = sum_{i=0}^{4095} k[i] * kz[i + 8191 - s], s in [0,8192)
__global__ void k_autocorr(const float* __restrict__ k,
                           const float* __restrict__ kz,
                           float* __restrict__ g) {
  int s = blockIdx.x * 256 + threadIdx.x;
  const float* kzs = kz + (8191 - s);
  float a0 = 0.f, a1 = 0.f, a2 = 0.f, a3 = 0.f;
  #pragma unroll 4
  for (int i = 0; i < 4096; i += 4) {
    a0 = fmaf(k[i],     kzs[i],     a0);
    a1 = fmaf(k[i + 1], kzs[i + 1], a1);
    a2 = fmaf(k[i + 2], kzs[i + 2], a2);
    a3 = fmaf(k[i + 3], kzs[i + 3], a3);
  }
  g[s] = (a0 + a1) + (a2 + a3);
}

// K2: build Toeplitz A fragments, fragment-ordered (chunk P, lane l, 8 bf16).
// A_p[i][k] = gpad[32p + k - i], lane l holds i = l&15, k = (l>>4)*8 + jj.
__global__ void k_build_afrag(const float* __restrict__ g,
                              __bf16* __restrict__ Ahi,
                              __bf16* __restrict__ Alo) {
  int P = blockIdx.x;              // 0..272
  int t = threadIdx.x;             // 256 threads: l = t>>2, two jj each
  int l = t >> 2;
  int jj0 = (t & 3) * 2;
  int q = l >> 4, i = l & 15;
  int p = P - 8;
  #pragma unroll
  for (int u = 0; u < 2; ++u) {
    int jj = jj0 + u;
    int s = 32 * p + 8 * q + jj - i;
    float val = (s >= 0 && s <= 8190) ? g[s] : 0.0f;
    __bf16 hi = (__bf16)val;
    __bf16 lo = (__bf16)(val - (float)hi);
    int off = P * 512 + l * 8 + jj;
    Ahi[off] = hi;
    Alo[off] = lo;
  }
}

// K3: xe[row][w] = bf16( X(w - 4095) ): reflect inside [-2048, T+2048), else 0
__global__ void k_build_xe(const float* __restrict__ x, __bf16* __restrict__ xe) {
  int idx = blockIdx.x * 256 + threadIdx.x;    // 0..139775
  int row = blockIdx.y;
  if (idx >= XE_LEN) return;
  int v = idx - 4095;
  float val = 0.0f;
  if (v >= -2048 && v < T_LEN + 2048) {
    int v2 = v < 0 ? -v : v;
    v2 = v2 >= T_LEN ? 2 * T_LEN - 2 - v2 : v2;
    val = x[(size_t)row * T_LEN + v2];
  }
  xe[(size_t)row * XE_LEN + idx] = (__bf16)val;
}

// Main: each wave = 4 rows x 2 time-tiles (512 outputs); block = 4 waves =
// 16 rows, same t0 (A-fragments shared via L1). Diagonal B-sharing: at
// chunk-position Q, tile mt uses A chunk p = Q - 8*mt; B depends only on Q.
__global__ __launch_bounds__(256) void k_fir_mfma(
    const __bf16* __restrict__ xe, const uint4* __restrict__ Ahi,
    const uint4* __restrict__ Alo, float* __restrict__ out) {
  const int tid = threadIdx.x;
  const int wv = tid >> 6;
  const int l = tid & 63;
  const int q = l >> 4;
  const int n = l & 15;
  const int t0 = blockIdx.x << 9;              // 512 outputs per block
  const int r0 = blockIdx.y * 16 + wv * 4;

  const uint4* xb0 = (const uint4*)(xe + (size_t)(r0 + 0) * XE_LEN);
  const uint4* xb1 = (const uint4*)(xe + (size_t)(r0 + 1) * XE_LEN);
  const uint4* xb2 = (const uint4*)(xe + (size_t)(r0 + 2) * XE_LEN);
  const uint4* xb3 = (const uint4*)(xe + (size_t)(r0 + 3) * XE_LEN);
  const int lofs = q + 2 * n;                  // uint4 units within B window

  f32x4 z = {0.f, 0.f, 0.f, 0.f};
  f32x4 acc00 = z, acc01 = z, acc10 = z, acc11 = z;
  f32x4 acc20 = z, acc21 = z, acc30 = z, acc31 = z;

  for (int Q = 0; Q < QSTEPS; ++Q) {
    const int bb = ((t0 + (Q << 5)) >> 3) + lofs;
    uint4 ub0 = xb0[bb];
    uint4 ub1 = xb1[bb];
    uint4 ub2 = xb2[bb];
    uint4 ub3 = xb3[bb];
    const int ai0 = (Q + 8) * 64 + l;          // tile mt=0: chunk p = Q
    const int ai1 = Q * 64 + l;                // tile mt=1: chunk p = Q - 8
    bf16x8 A0h = __builtin_bit_cast(bf16x8, Ahi[ai0]);
    bf16x8 A0l = __builtin_bit_cast(bf16x8, Alo[ai0]);
    bf16x8 A1h = __builtin_bit_cast(bf16x8, Ahi[ai1]);
    bf16x8 A1l = __builtin_bit_cast(bf16x8, Alo[ai1]);
    bf16x8 B0 = __builtin_bit_cast(bf16x8, ub0);
    bf16x8 B1 = __builtin_bit_cast(bf16x8, ub1);
    bf16x8 B2 = __builtin_bit_cast(bf16x8, ub2);
    bf16x8 B3 = __builtin_bit_cast(bf16x8, ub3);

    acc00 = __builtin_amdgcn_mfma_f32_16x16x32_bf16(A0h, B0, acc00, 0, 0, 0);
    acc00 = __builtin_amdgcn_mfma_f32_16x16x32_bf16(A0l, B0, acc00, 0, 0, 0);
    acc01 = __builtin_amdgcn_mfma_f32_16x16x32_bf16(A1h, B0, acc01, 0, 0, 0);
    acc01 = __builtin_amdgcn_mfma_f32_16x16x32_bf16(A1l, B0, acc01, 0, 0, 0);

    acc10 = __builtin_amdgcn_mfma_f32_16x16x32_bf16(A0h, B1, acc10, 0, 0, 0);
    acc10 = __builtin_amdgcn_mfma_f32_16x16x32_bf16(A0l, B1, acc10, 0, 0, 0);
    acc11 = __builtin_amdgcn_mfma_f32_16x16x32_bf16(A1h, B1, acc11, 0, 0, 0);
    acc11 = __builtin_amdgcn_mfma_f32_16x16x32_bf16(A1l, B1, acc11, 0, 0, 0);

    acc20 = __builtin_amdgcn_mfma_f32_16x16x32_bf16(A0h, B2, acc20, 0, 0, 0);
    acc20 = __builtin_amdgcn_mfma_f32_16x16x32_bf16(A0l, B2, acc20, 0, 0, 0);
    acc21 = __builtin_amdgcn_mfma_f32_16x16x32_bf16(A1h, B2, acc21, 0, 0, 0);
    acc21 = __builtin_amdgcn_mfma_f32_16x16x32_bf16(A1l, B2, acc21, 0, 0, 0);

    acc30 = __builtin_amdgcn_mfma_f32_16x16x32_bf16(A0h, B3, acc30, 0, 0, 0);
    acc30 = __builtin_amdgcn_mfma_f32_16x16x32_bf16(A0l, B3, acc30, 0, 0, 0);
    acc31 = __builtin_amdgcn_mfma_f32_16x16x32_bf16(A1h, B3, acc31, 0, 0, 0);
    acc31 = __builtin_amdgcn_mfma_f32_16x16x32_bf16(A1l, B3, acc31, 0, 0, 0);
  }

  // C/D layout: col(j) = lane&15, row(i) = (lane>>4)*4 + reg.
  // Output t = t0 + 256*mt + i + 16*j  -> 4 consecutive floats per lane.
  const int co = (q << 2) + (n << 4);
  float* d0 = out + (size_t)(r0 + 0) * T_LEN + t0 + co;
  *(f32x4*)d0 = acc00;  *(f32x4*)(d0 + 256) = acc01;
  float* d1 = out + (size_t)(r0 + 1) * T_LEN + t0 + co;
  *(f32x4*)d1 = acc10;  *(f32x4*)(d1 + 256) = acc11;
  float* d2 = out + (size_t)(r0 + 2) * T_LEN + t0 + co;
  *(f32x4*)d2 = acc20;  *(f32x4*)(d2 + 256) = acc21;
  float* d3 = out + (size_t)(r0 + 3) * T_LEN + t0 + co;
  *(f32x4*)d3 = acc30;  *(f32x4*)(d3 + 256) = acc31;
}

extern "C" void kernel_launch(void* const* d_in, const int* in_sizes, int n_in,
                              void* d_out, int out_size, void* d_ws, size_t ws_size,
                              hipStream_t stream) {
  const float* x = (const float*)d_in[0];
  const float* k = (const float*)d_in[1];
  float* out = (float*)d_out;
  char* ws = (char*)d_ws;
  if (ws_size < (size_t)WS_END) return;   // need ~9.6 MB scratch

  float*  kz  = (float*)(ws + WS_KZ);
  float*  g   = (float*)(ws + WS_G);
  __bf16* Ahi = (__bf16*)(ws + WS_AHI);
  __bf16* Alo = (__bf16*)(ws + WS_ALO);
  __bf16* xe  = (__bf16*)(ws + WS_XE);

  k_build_kz<<<dim3(48), dim3(256), 0, stream>>>(k, kz);
  k_autocorr<<<dim3(32), dim3(256), 0, stream>>>(k, kz, g);
  k_build_afrag<<<dim3(NCHUNK), dim3(256), 0, stream>>>(g, Ahi, Alo);
  k_build_xe<<<dim3(XE_LEN / 256, 32), dim3(256), 0, stream>>>(x, xe);
  k_fir_mfma<<<dim3(T_LEN / 512, 2), dim3(256), 0, stream>>>(
      xe, (const uint4*)Ahi, (const uint4*)Alo, out);
}

// Round 2
// 234.101 us; speedup vs baseline: 1.4856x; 1.4856x over previous
//
#include <hip/hip_runtime.h>

// Zero-phase bandpass FIR = one 8191-tap correlation with the kernel
// autocorrelation g, run on MFMA as an implicit-Toeplitz GEMM.
//   out[t] = sum_{s=0}^{8190} g[s] * xe[t + s]
// Round 2: hi-only bf16 g (dropped-lo error ~0.004, threshold 0.075),
// R=4 rows x T=4 time-tiles per wave, B staged through double-buffered LDS
// (256 B/MFMA LDS + 256 B/MFMA L1 for A, both under budget -> MFMA-bound),
// split-K autocorr (was ~100us VMEM-issue bound at 32 blocks).

#define T_LEN   131072
#define XE_LEN  139776            // covers t0max + 32*280 + 271 = 139279
#define XE_U4   (XE_LEN / 8)      // 17472 uint4 per row
#define NCHUNK  305               // A chunks: p in [-24, 280], P = p + 24
#define QSTEPS  281
#define SC      32                // Q-steps per LDS chunk
#define NCH_Q   9                 // ceil(281/32); last chunk = 25 Qs
#define ROWS_PB 8                 // rows per block (2 waves x 4)
#define CW      160               // staged uint4s per row per chunk (need 158)

typedef float  f32x4  __attribute__((ext_vector_type(4)));
typedef __bf16 bf16x8 __attribute__((ext_vector_type(8)));

// ---------- ws layout (bytes) ----------
#define WS_KZ   0                 // 12288 floats (zero-padded k)
#define WS_G    49152             // 8192 floats  (autocorrelation)
#define WS_AHI  81920             // 305*512 bf16 Toeplitz frags = 312320 B
#define WS_XE   394240            // 32*139776 bf16 padded signal
#define WS_END  9339904

// K0: kz[m] = k[m-4096] if in range else 0, m in [0,12288)
__global__ void k_build_kz(const float* __restrict__ k, float* __restrict__ kz) {
  int m = blockIdx.x * 256 + threadIdx.x;
  if (m < 12288) {
    int i = m - 4096;
    kz[m] = (i >= 0 && i < 4096) ? k[i] : 0.0f;
  }
}

// K1: g[s] += partial over i-chunk; grid (32, 16), g pre-zeroed by memset.
__global__ void k_autocorr(const float* __restrict__ k,
                           const float* __restrict__ kz,
                           float* __restrict__ g) {
  int s = blockIdx.x * 256 + threadIdx.x;
  int i0 = blockIdx.y * 256;
  const float* kk  = k + i0;
  const float* kzs = kz + (8191 - s) + i0;   // coalesced across s
  float a0 = 0.f, a1 = 0.f, a2 = 0.f, a3 = 0.f;
  #pragma unroll 8
  for (int i = 0; i < 256; i += 4) {
    a0 = fmaf(kk[i],     kzs[i],     a0);
    a1 = fmaf(kk[i + 1], kzs[i + 1], a1);
    a2 = fmaf(kk[i + 2], kzs[i + 2], a2);
    a3 = fmaf(kk[i + 3], kzs[i + 3], a3);
  }
  atomicAdd(&g[s], (a0 + a1) + (a2 + a3));
}

// K2: Toeplitz A fragments (hi only), fragment-ordered (chunk P, lane l, 8 bf16).
// A_p[i][k] = gpad[32p + k - i], lane l: i = l&15, k = (l>>4)*8 + jj.
__global__ void k_build_afrag(const float* __restrict__ g,
                              __bf16* __restrict__ Ahi) {
  int P = blockIdx.x;              // 0..304
  int t = threadIdx.x;             // l = t>>2, two jj per thread
  int l = t >> 2;
  int jj0 = (t & 3) * 2;
  int q = l >> 4, i = l & 15;
  int p = P - 24;
  #pragma unroll
  for (int u = 0; u < 2; ++u) {
    int jj = jj0 + u;
    int s = 32 * p + 8 * q + jj - i;
    float val = (s >= 0 && s <= 8190) ? g[s] : 0.0f;
    Ahi[P * 512 + l * 8 + jj] = (__bf16)val;
  }
}

// K3: xe[row][w] = bf16( X(w - 4095) ): reflect inside [-2048, T+2048), else 0
__global__ void k_build_xe(const float* __restrict__ x, __bf16* __restrict__ xe) {
  int idx = blockIdx.x * 256 + threadIdx.x;
  int row = blockIdx.y;
  if (idx >= XE_LEN) return;
  int v = idx - 4095;
  float val = 0.0f;
  if (v >= -2048 && v < T_LEN + 2048) {
    int v2 = v < 0 ? -v : v;
    v2 = v2 >= T_LEN ? 2 * T_LEN - 2 - v2 : v2;
    val = x[(size_t)row * T_LEN + v2];
  }
  xe[(size_t)row * XE_LEN + idx] = (__bf16)val;
}

// Main: block = 128 threads (2 waves), 8 rows, 1024 outputs (T=4 tiles/wave).
// Grid (128, 4) = 512 blocks = 2/CU. B via double-buffered LDS; A via L1
// (shared by all waves/blocks at the same Q). Diagonal identity: at Q, tile
// mt uses A chunk p = Q - 8*mt against the SAME B fragment.
__global__ __launch_bounds__(128) void k_fir_mfma(
    const uint4* __restrict__ xeu, const uint4* __restrict__ Ahi,
    float* __restrict__ out) {
  __shared__ uint4 sb[2][ROWS_PB * CW];

  const int tid = threadIdx.x;
  const int wv  = tid >> 6;
  const int l   = tid & 63;
  const int q   = l >> 4;
  const int n   = l & 15;
  const int t0  = blockIdx.x << 10;          // 1024 outputs per block
  const int rbase = blockIdx.y * ROWS_PB;
  const int lofs = q + 2 * n;                // uint4 offset within B window

  // staging assignment: 16 threads per row, 10 uint4s each (CW=160)
  const int srow = tid >> 4;
  const int c0   = tid & 15;
  const uint4* gsrc = xeu + (size_t)(rbase + srow) * XE_U4 + (t0 >> 3);

  f32x4 acc[4][4];                           // [row r][tile mt]
  #pragma unroll
  for (int r = 0; r < 4; ++r)
    #pragma unroll
    for (int m = 0; m < 4; ++m) acc[r][m] = (f32x4){0.f, 0.f, 0.f, 0.f};

  // stage chunk 0
  #pragma unroll
  for (int u = 0; u < 10; ++u)
    sb[0][srow * CW + c0 + (u << 4)] = gsrc[c0 + (u << 4)];
  __syncthreads();

  uint4 pre[10];
  for (int ch = 0; ch < NCH_Q; ++ch) {
    const bool more = (ch + 1) < NCH_Q;
    if (more) {
      const uint4* gch = gsrc + ((ch + 1) << 7);   // +128 uint4 per chunk
      #pragma unroll
      for (int u = 0; u < 10; ++u) pre[u] = gch[c0 + (u << 4)];
    }

    const int Q0 = ch << 5;
    const int qcount = more ? SC : (QSTEPS - Q0);
    const uint4* bwv = &sb[ch & 1][(wv << 2) * CW + lofs];

    #pragma unroll 4
    for (int Qr = 0; Qr < qcount; ++Qr) {
      const int Q = Q0 + Qr;
      uint4 ub0 = bwv[0 * CW + 4 * Qr];
      uint4 ub1 = bwv[1 * CW + 4 * Qr];
      uint4 ub2 = bwv[2 * CW + 4 * Qr];
      uint4 ub3 = bwv[3 * CW + 4 * Qr];
      bf16x8 B0 = __builtin_bit_cast(bf16x8, ub0);
      bf16x8 B1 = __builtin_bit_cast(bf16x8, ub1);
      bf16x8 B2 = __builtin_bit_cast(bf16x8, ub2);
      bf16x8 B3 = __builtin_bit_cast(bf16x8, ub3);
      #pragma unroll
      for (int mt = 0; mt < 4; ++mt) {
        bf16x8 A = __builtin_bit_cast(bf16x8, Ahi[(Q + 24 - 8 * mt) * 64 + l]);
        acc[0][mt] = __builtin_amdgcn_mfma_f32_16x16x32_bf16(A, B0, acc[0][mt], 0, 0, 0);
        acc[1][mt] = __builtin_amdgcn_mfma_f32_16x16x32_bf16(A, B1, acc[1][mt], 0, 0, 0);
        acc[2][mt] = __builtin_amdgcn_mfma_f32_16x16x32_bf16(A, B2, acc[2][mt], 0, 0, 0);
        acc[3][mt] = __builtin_amdgcn_mfma_f32_16x16x32_bf16(A, B3, acc[3][mt], 0, 0, 0);
      }
    }

    if (more) {
      uint4* dst = &sb[(ch + 1) & 1][srow * CW];
      #pragma unroll
      for (int u = 0; u < 10; ++u) dst[c0 + (u << 4)] = pre[u];
    }
    __syncthreads();
  }

  // C/D layout: col(j)=lane&15, row(i)=(lane>>4)*4+reg; t = t0+256mt+i+16j.
  const int co = (q << 2) + (n << 4);
  #pragma unroll
  for (int r = 0; r < 4; ++r) {
    float* dst = out + (size_t)(rbase + (wv << 2) + r) * T_LEN + t0 + co;
    #pragma unroll
    for (int mt = 0; mt < 4; ++mt)
      *(f32x4*)(dst + (mt << 8)) = acc[r][mt];
  }
}

extern "C" void kernel_launch(void* const* d_in, const int* in_sizes, int n_in,
                              void* d_out, int out_size, void* d_ws, size_t ws_size,
                              hipStream_t stream) {
  const float* x = (const float*)d_in[0];
  const float* k = (const float*)d_in[1];
  float* out = (float*)d_out;
  char* ws = (char*)d_ws;
  if (ws_size < (size_t)WS_END) return;

  float*  kz  = (float*)(ws + WS_KZ);
  float*  g   = (float*)(ws + WS_G);
  __bf16* Ahi = (__bf16*)(ws + WS_AHI);
  __bf16* xe  = (__bf16*)(ws + WS_XE);

  k_build_kz<<<dim3(48), dim3(256), 0, stream>>>(k, kz);
  hipMemsetAsync(g, 0, 8192 * sizeof(float), stream);
  k_autocorr<<<dim3(32, 16), dim3(256), 0, stream>>>(k, kz, g);
  k_build_afrag<<<dim3(NCHUNK), dim3(256), 0, stream>>>(g, Ahi);
  k_build_xe<<<dim3(XE_LEN / 256, 32), dim3(256), 0, stream>>>(x, xe);
  k_fir_mfma<<<dim3(T_LEN / 1024, 4), dim3(128), 0, stream>>>(
      (const uint4*)xe, (const uint4*)Ahi, out);
}